// Round 9
// baseline (934.616 us; speedup 1.0000x reference)
//
#include <hip/hip_runtime.h>
#include <hip/hip_bf16.h>

typedef __attribute__((ext_vector_type(4))) float v4f;
typedef __attribute__((ext_vector_type(8))) short v8s;
typedef __attribute__((ext_vector_type(4))) unsigned v4u;
typedef __attribute__((ext_vector_type(2))) unsigned v2u;

// full RNE fp32->bf16 (prep kernel only)
__device__ __forceinline__ short f2bf(float f) {
  union { float f; unsigned u; } v; v.f = f;
  unsigned r = v.u + 0x7FFFu + ((v.u >> 16) & 1u);
  return (short)(r >> 16);
}
// packed 2xfp32 -> bf16x2, single v_cvt_pk_bf16_f32
__device__ __forceinline__ unsigned pk2(float a, float b) {
  union { __hip_bfloat162 h; unsigned u; } c;
  c.h = __float22bfloat162_rn(make_float2(a, b));
  return c.u;
}

// prep: pack W1 [128x256] + W2 [256x256] into bf16 MFMA A-fragment order
// (16x16x32: lane l of frag (mt,kt) holds A'[n=mt*16+(l&15)][k=kt*32+(l>>4)*8+j])
// and convert x_user/x_movie f32 -> bf16 tables (RNE; identical numerics to
// in-register conversion, half the gather bytes, cache-resident working set).
__global__ void prep(const float* __restrict__ W1, const float* __restrict__ W2,
                     const float* __restrict__ xu, const float* __restrict__ xm,
                     short* __restrict__ pW1, short* __restrict__ pW2,
                     short* __restrict__ xub, short* __restrict__ xmb,
                     int Nu, int Nm) {
  int tid = blockIdx.x * 256 + threadIdx.x;
  if (tid < 32768) {
    int j = tid & 7, l = (tid >> 3) & 63, frag = tid >> 9;
    int mt = frag >> 2, kt = frag & 3;
    int n = mt * 16 + (l & 15);
    int k = kt * 32 + ((l >> 4) * 8) + j;
    pW1[tid] = f2bf(W1[k * 256 + n]);
  } else if (tid < 98304) {
    int t2 = tid - 32768;
    int j = t2 & 7, l = (t2 >> 3) & 63, frag = t2 >> 9;
    int mt = frag >> 3, kt = frag & 7;
    int n = mt * 16 + (l & 15);
    int k = kt * 32 + ((l >> 4) * 8) + j;
    pW2[t2] = f2bf(W2[k * 256 + n]);
  } else {
    int c = tid - 98304;
    int tu = Nu * 8;
    int total = tu + Nm * 8;
    if (c < total) {
      const float* s; short* d;
      if (c < tu) { s = xu + (size_t)c * 8; d = xub + (size_t)c * 8; }
      else { int c2 = c - tu; s = xm + (size_t)c2 * 8; d = xmb + (size_t)c2 * 8; }
      v4f a = *(const v4f*)s, b = *(const v4f*)(s + 4);
      v4u o = { pk2(a[0], a[1]), pk2(a[2], a[3]), pk2(b[0], b[1]), pk2(b[2], b[3]) };
      *(v4u*)d = o;
    }
  }
}

#define LDH_S 264   // 256 + 8 pad shorts
#define LDP_S 20    // 16 slots + 4 pad floats
#define HBUF (64 * LDH_S)   // 16896 shorts / buffer
#define PBUF (64 * LDP_S)   // 1280 floats / buffer
#define SMEM_BYTES (2*HBUF*2 + 2*PBUF*4)   // 77824 B -> 2 blocks/CU

// v17: X-staging ELIMINATED. Key realizations from v12/v16 counters:
//  (1) VGPR_Count=108 < rW2's 128 => compiler streams W2 from L2 (never
//      register-resident) => the occupancy limiter was LDS (112.6 KB), not
//      registers.
//  (2) v16: +50% waves in ONE barrier group = flat (duplicated LDS reads
//      cancel). Independent blocks are different: separate barrier groups,
//      one block's drain hides under the other's compute.
// The L1 B-fragment (8 consecutive feats of one edge) is a contiguous 16B
// chunk of the bf16 feature table, so A-waves load it DIRECTLY from global
// (L2/L3-resident) with per-lane edge indices prefetched one tile ahead.
// Deletes: gather/commit stage, both ldsX buffers (-34.8 KB), their LDS
// traffic+conflicts; pipeline now 2-deep. SMEM 77.8 KB -> 2 blocks/CU,
// 4 waves/SIMD (launch_bounds cap 128 VGPR; v12 demand was 108).
// Phase k (one barrier):  A: P-store(t_{k-2}) | L1(t_k): global frags ->
// MFMA -> ldsH[pb] | idx prefetch t_{k+2}.   B: L2(t_{k-1}) from ldsH[pb^1]
// -> ldsP[pb]. B inner loop is v12 verbatim.
__global__ __launch_bounds__(512, 4) void mlp_v17(
    const short* __restrict__ xub, const short* __restrict__ xmb,
    const void* __restrict__ eidx,
    const short* __restrict__ pW1, const short* __restrict__ pW2,
    const float* __restrict__ b1, const float* __restrict__ b2,
    const float* __restrict__ W3, const float* __restrict__ b3,
    float* __restrict__ out, int E)
{
  extern __shared__ __align__(16) char smem[];
  short* ldsH = (short*)smem;                       // [2][HBUF]
  float* ldsP = (float*)(smem + 2 * HBUF * 2);      // [2][PBUF]

  const int t    = threadIdx.x;
  const int w    = t >> 6;
  const int lane = t & 63;
  const int quad = lane >> 4;
  const int lp   = lane & 15;
  const int wg   = w >> 1;
  const bool isA = (((w & 1) ^ ((w >> 2) & 1)) == 0);

  const unsigned* ew = (const unsigned*)eidx;
  unsigned oddw = (lane < 32) ? ew[2 * lane + 1] : 0u;
  const bool i64 = (__ballot(oddw != 0u) == 0ull);

  const int ntiles = (E + 63) >> 6;
  const int S   = (int)gridDim.x;
  const int bid = (int)blockIdx.x;
  const int Tb  = (ntiles - bid + S - 1) / S;
  const float bias3 = b3[0];

  if (isA) {
    // ===== producer: L1 with direct-global B-fragments (+ P-store wg0) =====
    const v8s* w1v = (const v8s*)pW1;
    v8s rW1[4][4];
#pragma unroll
    for (int mi = 0; mi < 4; ++mi)
#pragma unroll
      for (int kt = 0; kt < 4; ++kt)
        rW1[mi][kt] = w1v[(((wg * 4 + mi) * 4) + kt) * 64 + lane];
    v4f rb1[4];
#pragma unroll
    for (int mi = 0; mi < 4; ++mi)
      rb1[mi] = *(const v4f*)(b1 + wg * 64 + mi * 16 + quad * 4);

    // per-lane edge indices: edge = ni*16 + lp for ni 0..3
    int rI[4], cI[4], rN[4], cN[4];
    auto loadIdxV = [&](int tl, int* r, int* c) {
#pragma unroll
      for (int ni = 0; ni < 4; ++ni) {
        int gE = tl * 64 + ni * 16 + lp;
        if (gE >= E || gE < 0) gE = 0;
        if (i64) {
          const long long* p = (const long long*)eidx;
          r[ni] = (int)p[gE]; c[ni] = (int)p[(long long)E + gE];
        } else {
          const int* p = (const int*)eidx;
          r[ni] = p[gE]; c[ni] = p[E + gE];
        }
      }
    };
    loadIdxV(bid, rI, cI);          // tile t_0
    loadIdxV(bid + S, rN, cN);      // tile t_1

    for (int k = 0; k <= Tb + 1; ++k) {
      __syncthreads();
      const int pb = k & 1;
      const int tg = bid + k * S;

      // ---- reduce + store tile t_{k-2} from ldsP[pb^1] (wave wg==0)
      if (k >= 2 && wg == 0) {
        const v4f* pp = (const v4f*)&ldsP[(pb ^ 1) * PBUF + lane * LDP_S];
        float r = bias3;
#pragma unroll
        for (int c = 0; c < 4; ++c) {
          v4f p = pp[c];
          r += (p[0] + p[1]) + (p[2] + p[3]);
        }
        int o = (tg - 2 * S) * 64 + lane;
        if (o < E) out[o] = r;
      }

      // ---- layer 1 of t_k : global frags -> ldsH[pb]
      if (k < Tb) {
        short* hb = &ldsH[pb * HBUF];
#pragma unroll
        for (int nh = 0; nh < 2; ++nh) {
          // B-fragments for edges (nh*2+n2)*16+lp, direct from tables:
          // kt 0,1 = user feats 0..63 ; kt 2,3 = movie feats 0..63
          v8s bf[2][4];
#pragma unroll
          for (int n2 = 0; n2 < 2; ++n2) {
            const int ni = nh * 2 + n2;
            const short* ub = xub + (size_t)(unsigned)rI[ni] * 64 + quad * 8;
            const short* mb = xmb + (size_t)(unsigned)cI[ni] * 64 + quad * 8;
            bf[n2][0] = *(const v8s*)(ub);
            bf[n2][1] = *(const v8s*)(ub + 32);
            bf[n2][2] = *(const v8s*)(mb);
            bf[n2][3] = *(const v8s*)(mb + 32);
          }
          v4f acc[4][2];
#pragma unroll
          for (int mi = 0; mi < 4; ++mi) { acc[mi][0] = rb1[mi]; acc[mi][1] = rb1[mi]; }
          __builtin_amdgcn_s_setprio(1);
#pragma unroll
          for (int kt = 0; kt < 4; ++kt)
#pragma unroll
            for (int mi = 0; mi < 4; ++mi) {
              acc[mi][0] = __builtin_amdgcn_mfma_f32_16x16x32_bf16(rW1[mi][kt], bf[0][kt], acc[mi][0], 0, 0, 0);
              acc[mi][1] = __builtin_amdgcn_mfma_f32_16x16x32_bf16(rW1[mi][kt], bf[1][kt], acc[mi][1], 0, 0, 0);
            }
          __builtin_amdgcn_s_setprio(0);
#pragma unroll
          for (int mi = 0; mi < 4; ++mi) {
            int nh0 = wg * 64 + mi * 16 + quad * 4;
#pragma unroll
            for (int nj = 0; nj < 2; ++nj) {
              int e = (nh * 2 + nj) * 16 + lp;
              v4f v = acc[mi][nj];
              v2u pw; pw.x = pk2(fmaxf(v[0], 0.f), fmaxf(v[1], 0.f));
              pw.y = pk2(fmaxf(v[2], 0.f), fmaxf(v[3], 0.f));
              *(v2u*)&hb[e * LDH_S + nh0] = pw;   // ds_write_b64
            }
          }
        }
        // rotate index prefetch: consume t_{k+1} next phase, fetch t_{k+2}
#pragma unroll
        for (int ni = 0; ni < 4; ++ni) { rI[ni] = rN[ni]; cI[ni] = cN[ni]; }
        if (k + 1 < Tb) loadIdxV(tg + 2 * S, rN, cN);
      }
    }
  } else {
    // ===== consumer: layer 2 + bias/ReLU + W3 fold (v12 inner loop) =====
    const v8s* w2v = (const v8s*)pW2;
    v8s rW2[4][8];
#pragma unroll
    for (int mi = 0; mi < 4; ++mi)
#pragma unroll
      for (int kt = 0; kt < 8; ++kt)
        rW2[mi][kt] = w2v[(((wg * 4 + mi) * 8) + kt) * 64 + lane];
    v4f rb2[4], rw3[4];
#pragma unroll
    for (int mi = 0; mi < 4; ++mi) {
      int nh0 = wg * 64 + mi * 16 + quad * 4;
      rb2[mi] = *(const v4f*)(b2 + nh0);
      rw3[mi] = *(const v4f*)(W3 + nh0);
    }

    for (int k = 0; k <= Tb + 1; ++k) {
      __syncthreads();
      const int pb = k & 1;
      const int tg = bid + k * S;
      // L2 of t_{k-1} from ldsH[pb^1] -> ldsP[pb]
      if (k >= 1 && (k - 1) < Tb) {
        const short* hbr = &ldsH[(pb ^ 1) * HBUF];
        float* pPw = &ldsP[pb * PBUF];
#pragma unroll 1
        for (int nh = 0; nh < 2; ++nh) {       // ni halves: acc live = 32 VGPR
          v4f acc2[4][2];
#pragma unroll
          for (int mi = 0; mi < 4; ++mi) { acc2[mi][0] = rb2[mi]; acc2[mi][1] = rb2[mi]; }
          __builtin_amdgcn_s_setprio(1);
#pragma unroll
          for (int kt = 0; kt < 8; ++kt) {
            v8s bf0 = *(const v8s*)&hbr[((nh * 2 + 0) * 16 + lp) * LDH_S + kt * 32 + quad * 8];
            v8s bf1 = *(const v8s*)&hbr[((nh * 2 + 1) * 16 + lp) * LDH_S + kt * 32 + quad * 8];
#pragma unroll
            for (int mi = 0; mi < 4; ++mi) {
              acc2[mi][0] = __builtin_amdgcn_mfma_f32_16x16x32_bf16(rW2[mi][kt], bf0, acc2[mi][0], 0, 0, 0);
              acc2[mi][1] = __builtin_amdgcn_mfma_f32_16x16x32_bf16(rW2[mi][kt], bf1, acc2[mi][1], 0, 0, 0);
            }
          }
          __builtin_amdgcn_s_setprio(0);
          float s0 = 0.f, s1 = 0.f;
#pragma unroll
          for (int mi = 0; mi < 4; ++mi) {
#pragma unroll
            for (int r = 0; r < 4; ++r) {
              s0 += fmaxf(acc2[mi][0][r], 0.f) * rw3[mi][r];
              s1 += fmaxf(acc2[mi][1][r], 0.f) * rw3[mi][r];
            }
          }
          int e0 = (nh * 2 + 0) * 16 + lp, e1 = (nh * 2 + 1) * 16 + lp;
          pPw[e0 * LDP_S + wg * 4 + quad] = s0;
          pPw[e1 * LDP_S + wg * 4 + quad] = s1;
        }
      }
    }
  }
}

extern "C" void kernel_launch(void* const* d_in, const int* in_sizes, int n_in,
                              void* d_out, int out_size, void* d_ws, size_t ws_size,
                              hipStream_t stream) {
  const float* xu  = (const float*)d_in[0];
  const float* xm  = (const float*)d_in[1];
  const void*  ei  = d_in[2];
  const float* W1  = (const float*)d_in[3];
  const float* b1  = (const float*)d_in[4];
  const float* W2  = (const float*)d_in[5];
  const float* b2  = (const float*)d_in[6];
  const float* W3  = (const float*)d_in[7];
  const float* b3  = (const float*)d_in[8];
  float* out = (float*)d_out;

  const int E  = in_sizes[2] / 2;
  const int Nu = in_sizes[0] / 64;
  const int Nm = in_sizes[1] / 64;

  short* pW1 = (short*)d_ws;          // 64 KB
  short* pW2 = pW1 + 32768;           // 128 KB
  short* xub = (short*)((char*)d_ws + 196608);
  short* xmb = xub + (size_t)Nu * 64;

  const int cvt_blocks = ((Nu + Nm) * 8 + 255) / 256;
  hipLaunchKernelGGL(prep, dim3(384 + cvt_blocks), dim3(256), 0, stream,
                     W1, W2, xu, xm, pW1, pW2, xub, xmb, Nu, Nm);

  hipFuncSetAttribute((const void*)mlp_v17,
                      hipFuncAttributeMaxDynamicSharedMemorySize, SMEM_BYTES);

  const int ntiles = (E + 63) / 64;
  const int nblk = ntiles < 512 ? ntiles : 512;   // 2 blocks/CU
  hipLaunchKernelGGL(mlp_v17, dim3(nblk), dim3(512), SMEM_BYTES, stream,
                     xub, xmb, ei, pW1, pW2, b1, b2, W3, b3, out, E);
}

// Round 10
// 571.679 us; speedup vs baseline: 1.6349x; 1.6349x over previous
//
#include <hip/hip_runtime.h>
#include <hip/hip_bf16.h>

typedef __attribute__((ext_vector_type(4))) float v4f;
typedef __attribute__((ext_vector_type(8))) short v8s;
typedef __attribute__((ext_vector_type(4))) unsigned v4u;
typedef __attribute__((ext_vector_type(2))) unsigned v2u;

// full RNE fp32->bf16 (prep kernel only)
__device__ __forceinline__ short f2bf(float f) {
  union { float f; unsigned u; } v; v.f = f;
  unsigned r = v.u + 0x7FFFu + ((v.u >> 16) & 1u);
  return (short)(r >> 16);
}
// packed 2xfp32 -> bf16x2, single v_cvt_pk_bf16_f32
__device__ __forceinline__ unsigned pk2(float a, float b) {
  union { __hip_bfloat162 h; unsigned u; } c;
  c.h = __float22bfloat162_rn(make_float2(a, b));
  return c.u;
}

// prep: pack W1 [128x256] + W2 [256x256] into bf16 MFMA A-fragment order
// (16x16x32: lane l of frag (mt,kt) holds A'[n=mt*16+(l&15)][k=kt*32+(l>>4)*8+j])
// and convert x_user/x_movie f32 -> bf16 tables (RNE; identical numerics to
// in-register conversion, half the gather bytes, cache-resident working set).
__global__ void prep(const float* __restrict__ W1, const float* __restrict__ W2,
                     const float* __restrict__ xu, const float* __restrict__ xm,
                     short* __restrict__ pW1, short* __restrict__ pW2,
                     short* __restrict__ xub, short* __restrict__ xmb,
                     int Nu, int Nm) {
  int tid = blockIdx.x * 256 + threadIdx.x;
  if (tid < 32768) {
    int j = tid & 7, l = (tid >> 3) & 63, frag = tid >> 9;
    int mt = frag >> 2, kt = frag & 3;
    int n = mt * 16 + (l & 15);
    int k = kt * 32 + ((l >> 4) * 8) + j;
    pW1[tid] = f2bf(W1[k * 256 + n]);
  } else if (tid < 98304) {
    int t2 = tid - 32768;
    int j = t2 & 7, l = (t2 >> 3) & 63, frag = t2 >> 9;
    int mt = frag >> 3, kt = frag & 7;
    int n = mt * 16 + (l & 15);
    int k = kt * 32 + ((l >> 4) * 8) + j;
    pW2[t2] = f2bf(W2[k * 256 + n]);
  } else {
    int c = tid - 98304;
    int tu = Nu * 8;
    int total = tu + Nm * 8;
    if (c < total) {
      const float* s; short* d;
      if (c < tu) { s = xu + (size_t)c * 8; d = xub + (size_t)c * 8; }
      else { int c2 = c - tu; s = xm + (size_t)c2 * 8; d = xmb + (size_t)c2 * 8; }
      v4f a = *(const v4f*)s, b = *(const v4f*)(s + 4);
      v4u o = { pk2(a[0], a[1]), pk2(a[2], a[3]), pk2(b[0], b[1]), pk2(b[2], b[3]) };
      *(v4u*)d = o;
    }
  }
}

#define TIL 32      // edges per tile (halved from v12)
#define LDX_S 136   // 128 + 8 pad shorts
#define LDH_S 264   // 256 + 8 pad shorts
#define LDP_S 20    // 16 slots + 4 pad floats
#define XBUF (TIL * LDX_S)   // 4352 shorts / buffer
#define HBUF (TIL * LDH_S)   // 8448 shorts / buffer
#define PBUF (TIL * LDP_S)   // 640 floats / buffer
#define SMEM_BYTES (2*XBUF*2 + 2*HBUF*2 + 2*PBUF*4)   // 56320 B -> 2 blocks/CU

// v18 = v12's exact staging/roles/pipeline at HALF TILE (32 edges) so SMEM =
// 56.3 KB -> TWO INDEPENDENT BLOCKS per CU (4 waves/SIMD). Evidence chain:
//  - v12: latency-bound at 2 waves/SIMD, both pipes ~50%, FETCH 94 MB.
//  - v16: +waves in the SAME barrier group = flat (duplicated LDS reads).
//  - v17: 2 blocks/CU reached occupancy 44.8% (lever works) but its
//    direct-global gather duplicated HBM traffic 30x (FETCH 2.75 GB) = fatal.
// v18 keeps v12's single-copy gather->LDS staging (FETCH stays 94 MB) and
// gets the independent-block overlap: one block's barrier-drain windows are
// filled by the other block's compute. Grid doubles to 512 blocks; phases
// per block unchanged (~61); per-CU MFMA/LDS/gather totals identical to v12.
// Inner loops are v12's nh=0 half verbatim; VGPR demand ~108 < (512,4) cap 128.
__global__ __launch_bounds__(512, 4) void mlp_v18(
    const short* __restrict__ xub, const short* __restrict__ xmb,
    const void* __restrict__ eidx,
    const short* __restrict__ pW1, const short* __restrict__ pW2,
    const float* __restrict__ b1, const float* __restrict__ b2,
    const float* __restrict__ W3, const float* __restrict__ b3,
    float* __restrict__ out, int E)
{
  extern __shared__ __align__(16) char smem[];
  short* ldsX = (short*)smem;                       // [2][XBUF]
  short* ldsH = (short*)(smem + 2 * XBUF * 2);      // [2][HBUF]
  float* ldsP = (float*)(smem + 2 * XBUF * 2 + 2 * HBUF * 2); // [2][PBUF]

  const int t    = threadIdx.x;
  const int w    = t >> 6;
  const int lane = t & 63;
  const int quad = lane >> 4;
  const int lp   = lane & 15;
  const int wg   = w >> 1;
  const bool isA = (((w & 1) ^ ((w >> 2) & 1)) == 0);

  const unsigned* ew = (const unsigned*)eidx;
  unsigned oddw = (lane < 32) ? ew[2 * lane + 1] : 0u;
  const bool i64 = (__ballot(oddw != 0u) == 0ull);

  const int ntiles = (E + TIL - 1) / TIL;
  const int S   = (int)gridDim.x;
  const int bid = (int)blockIdx.x;
  const int Tb  = (ntiles - bid + S - 1) / S;
  const float bias3 = b3[0];

  if (isA) {
    // ===== producer: gather (bf16) + layer 1 (+ store on wg==0) =====
    const v8s* w1v = (const v8s*)pW1;
    v8s rW1[4][4];
#pragma unroll
    for (int mi = 0; mi < 4; ++mi)
#pragma unroll
      for (int kt = 0; kt < 4; ++kt)
        rW1[mi][kt] = w1v[(((wg * 4 + mi) * 4) + kt) * 64 + lane];
    v4f rb1[4];
#pragma unroll
    for (int mi = 0; mi < 4; ++mi)
      rb1[mi] = *(const v4f*)(b1 + wg * 64 + mi * 16 + quad * 4);

    const int ra = wg * 64 + lane;      // 0..255 : 8 threads/edge
    const int gi = ra >> 3;             // edge in tile 0..31
    const int gq = ra & 7;              // 8-feat chunk 0..7

    auto loadIdx = [&](int tl, int& row, int& col) {
      int gE = tl * TIL + gi;
      if (gE >= E || gE < 0) gE = 0;
      if (i64) {
        const long long* p = (const long long*)eidx;
        row = (int)p[gE]; col = (int)p[(long long)E + gE];
      } else {
        const int* p = (const int*)eidx;
        row = p[gE]; col = p[E + gE];
      }
    };

    v4u u0, m0;   // 8 bf16 per side
    auto issueUM = [&](int row, int col) {
      u0 = *(const v4u*)(xub + (size_t)row * 64 + gq * 8);
      m0 = *(const v4u*)(xmb + (size_t)col * 64 + gq * 8);
    };

    int rowN, colN;
    loadIdx(bid, rowN, colN);
    issueUM(rowN, colN);
    loadIdx(bid + S, rowN, colN);

    for (int k = 0; k <= Tb + 2; ++k) {
      __syncthreads();
      const int pb = k & 1;
      const int tg = bid + k * S;

      // ---- commit prefetched bf16 features -> ldsX[pb]
      if (k < Tb) {
        short* px = &ldsX[pb * XBUF + gi * LDX_S + gq * 8];
        *(v4u*)(px)      = u0;   // user  -> k 0..63
        *(v4u*)(px + 64) = m0;   // movie -> k 64..127
      }
      // ---- prefetch features(t_{k+1}), indices(t_{k+2})
      if (k + 1 < Tb) {
        issueUM(rowN, colN);
        loadIdx(tg + 2 * S, rowN, colN);
      }

      // ---- reduce + store tile t3 from ldsP[pb^1] (wave wg==0, lane<32)
      const int t3 = tg - 3 * S;
      if (t3 >= 0 && wg == 0 && lane < TIL) {
        const v4f* pp = (const v4f*)&ldsP[(pb ^ 1) * PBUF + lane * LDP_S];
        float r = bias3;
#pragma unroll
        for (int c = 0; c < 4; ++c) {
          v4f p = pp[c];
          r += (p[0] + p[1]) + (p[2] + p[3]);
        }
        int o = t3 * TIL + lane;
        if (o < E) out[o] = r;
      }

      // ---- layer 1 of t1 : ldsX[pb^1] -> ldsH[pb^1]
      const int t1 = tg - S;
      if (t1 >= 0 && t1 < ntiles) {
        const short* xb = &ldsX[(pb ^ 1) * XBUF];
        v4f acc[4][2];
#pragma unroll
        for (int mi = 0; mi < 4; ++mi) { acc[mi][0] = rb1[mi]; acc[mi][1] = rb1[mi]; }
        __builtin_amdgcn_s_setprio(1);
#pragma unroll
        for (int kt = 0; kt < 4; ++kt) {
          v8s bf0 = *(const v8s*)&xb[(lp) * LDX_S + kt * 32 + quad * 8];
          v8s bf1 = *(const v8s*)&xb[(16 + lp) * LDX_S + kt * 32 + quad * 8];
#pragma unroll
          for (int mi = 0; mi < 4; ++mi) {
            acc[mi][0] = __builtin_amdgcn_mfma_f32_16x16x32_bf16(rW1[mi][kt], bf0, acc[mi][0], 0, 0, 0);
            acc[mi][1] = __builtin_amdgcn_mfma_f32_16x16x32_bf16(rW1[mi][kt], bf1, acc[mi][1], 0, 0, 0);
          }
        }
        __builtin_amdgcn_s_setprio(0);
#pragma unroll
        for (int mi = 0; mi < 4; ++mi) {
          int nh0 = wg * 64 + mi * 16 + quad * 4;
#pragma unroll
          for (int nj = 0; nj < 2; ++nj) {
            int e = nj * 16 + lp;
            v4f v = acc[mi][nj];
            v2u pw; pw.x = pk2(fmaxf(v[0], 0.f), fmaxf(v[1], 0.f));
            pw.y = pk2(fmaxf(v[2], 0.f), fmaxf(v[3], 0.f));
            *(v2u*)&ldsH[(pb ^ 1) * HBUF + e * LDH_S + nh0] = pw;
          }
        }
      }
    }
  } else {
    // ===== consumer: layer 2 + bias/ReLU + W3 fold =====
    const v8s* w2v = (const v8s*)pW2;
    v8s rW2[4][8];
#pragma unroll
    for (int mi = 0; mi < 4; ++mi)
#pragma unroll
      for (int kt = 0; kt < 8; ++kt)
        rW2[mi][kt] = w2v[(((wg * 4 + mi) * 8) + kt) * 64 + lane];
    v4f rb2[4], rw3[4];
#pragma unroll
    for (int mi = 0; mi < 4; ++mi) {
      int nh0 = wg * 64 + mi * 16 + quad * 4;
      rb2[mi] = *(const v4f*)(b2 + nh0);
      rw3[mi] = *(const v4f*)(W3 + nh0);
    }

    for (int k = 0; k <= Tb + 2; ++k) {
      __syncthreads();
      const int pb = k & 1;
      const int tg = bid + k * S;
      const int t2 = tg - 2 * S;
      if (t2 >= 0 && t2 < ntiles) {
        const short* hbr = &ldsH[pb * HBUF];
        float* pPw = &ldsP[pb * PBUF];
        v4f acc2[4][2];
#pragma unroll
        for (int mi = 0; mi < 4; ++mi) { acc2[mi][0] = rb2[mi]; acc2[mi][1] = rb2[mi]; }
        __builtin_amdgcn_s_setprio(1);
#pragma unroll
        for (int kt = 0; kt < 8; ++kt) {
          v8s bf0 = *(const v8s*)&hbr[(lp) * LDH_S + kt * 32 + quad * 8];
          v8s bf1 = *(const v8s*)&hbr[(16 + lp) * LDH_S + kt * 32 + quad * 8];
#pragma unroll
          for (int mi = 0; mi < 4; ++mi) {
            acc2[mi][0] = __builtin_amdgcn_mfma_f32_16x16x32_bf16(rW2[mi][kt], bf0, acc2[mi][0], 0, 0, 0);
            acc2[mi][1] = __builtin_amdgcn_mfma_f32_16x16x32_bf16(rW2[mi][kt], bf1, acc2[mi][1], 0, 0, 0);
          }
        }
        __builtin_amdgcn_s_setprio(0);
        float s0 = 0.f, s1 = 0.f;
#pragma unroll
        for (int mi = 0; mi < 4; ++mi) {
#pragma unroll
          for (int r = 0; r < 4; ++r) {
            s0 += fmaxf(acc2[mi][0][r], 0.f) * rw3[mi][r];
            s1 += fmaxf(acc2[mi][1][r], 0.f) * rw3[mi][r];
          }
        }
        pPw[(lp) * LDP_S + wg * 4 + quad] = s0;
        pPw[(16 + lp) * LDP_S + wg * 4 + quad] = s1;
      }
    }
  }
}

extern "C" void kernel_launch(void* const* d_in, const int* in_sizes, int n_in,
                              void* d_out, int out_size, void* d_ws, size_t ws_size,
                              hipStream_t stream) {
  const float* xu  = (const float*)d_in[0];
  const float* xm  = (const float*)d_in[1];
  const void*  ei  = d_in[2];
  const float* W1  = (const float*)d_in[3];
  const float* b1  = (const float*)d_in[4];
  const float* W2  = (const float*)d_in[5];
  const float* b2  = (const float*)d_in[6];
  const float* W3  = (const float*)d_in[7];
  const float* b3  = (const float*)d_in[8];
  float* out = (float*)d_out;

  const int E  = in_sizes[2] / 2;
  const int Nu = in_sizes[0] / 64;
  const int Nm = in_sizes[1] / 64;

  short* pW1 = (short*)d_ws;          // 64 KB
  short* pW2 = pW1 + 32768;           // 128 KB
  short* xub = (short*)((char*)d_ws + 196608);
  short* xmb = xub + (size_t)Nu * 64;

  const int cvt_blocks = ((Nu + Nm) * 8 + 255) / 256;
  hipLaunchKernelGGL(prep, dim3(384 + cvt_blocks), dim3(256), 0, stream,
                     W1, W2, xu, xm, pW1, pW2, xub, xmb, Nu, Nm);

  hipFuncSetAttribute((const void*)mlp_v18,
                      hipFuncAttributeMaxDynamicSharedMemorySize, SMEM_BYTES);

  const int ntiles = (E + TIL - 1) / TIL;
  const int nblk = ntiles < 512 ? ntiles : 512;   // 2 blocks/CU
  hipLaunchKernelGGL(mlp_v18, dim3(nblk), dim3(512), SMEM_BYTES, stream,
                     xub, xmb, ei, pW1, pW2, b1, b2, W3, b3, out, E);
}

// Round 13
// 254.579 us; speedup vs baseline: 3.6712x; 2.2456x over previous
//
#include <hip/hip_runtime.h>
#include <hip/hip_bf16.h>

typedef __attribute__((ext_vector_type(4))) float v4f;
typedef __attribute__((ext_vector_type(8))) short v8s;
typedef __attribute__((ext_vector_type(4))) unsigned v4u;
typedef __attribute__((ext_vector_type(2))) unsigned v2u;

// full RNE fp32->bf16 (prep kernel only)
__device__ __forceinline__ short f2bf(float f) {
  union { float f; unsigned u; } v; v.f = f;
  unsigned r = v.u + 0x7FFFu + ((v.u >> 16) & 1u);
  return (short)(r >> 16);
}
// packed 2xfp32 -> bf16x2, single v_cvt_pk_bf16_f32
__device__ __forceinline__ unsigned pk2(float a, float b) {
  union { __hip_bfloat162 h; unsigned u; } c;
  c.h = __float22bfloat162_rn(make_float2(a, b));
  return c.u;
}

// prep: pack W1 [128x256] + W2 [256x256] into bf16 MFMA A-fragment order
// (16x16x32: lane l of frag (mt,kt) holds A'[n=mt*16+(l&15)][k=kt*32+(l>>4)*8+j])
// and convert x_user/x_movie f32 -> bf16 tables (RNE; identical numerics to
// in-register conversion, half the gather bytes, cache-resident working set).
__global__ void prep(const float* __restrict__ W1, const float* __restrict__ W2,
                     const float* __restrict__ xu, const float* __restrict__ xm,
                     short* __restrict__ pW1, short* __restrict__ pW2,
                     short* __restrict__ xub, short* __restrict__ xmb,
                     int Nu, int Nm) {
  int tid = blockIdx.x * 256 + threadIdx.x;
  if (tid < 32768) {
    int j = tid & 7, l = (tid >> 3) & 63, frag = tid >> 9;
    int mt = frag >> 2, kt = frag & 3;
    int n = mt * 16 + (l & 15);
    int k = kt * 32 + ((l >> 4) * 8) + j;
    pW1[tid] = f2bf(W1[k * 256 + n]);
  } else if (tid < 98304) {
    int t2 = tid - 32768;
    int j = t2 & 7, l = (t2 >> 3) & 63, frag = t2 >> 9;
    int mt = frag >> 3, kt = frag & 7;
    int n = mt * 16 + (l & 15);
    int k = kt * 32 + ((l >> 4) * 8) + j;
    pW2[t2] = f2bf(W2[k * 256 + n]);
  } else {
    int c = tid - 98304;
    int tu = Nu * 8;
    int total = tu + Nm * 8;
    if (c < total) {
      const float* s; short* d;
      if (c < tu) { s = xu + (size_t)c * 8; d = xub + (size_t)c * 8; }
      else { int c2 = c - tu; s = xm + (size_t)c2 * 8; d = xmb + (size_t)c2 * 8; }
      v4f a = *(const v4f*)s, b = *(const v4f*)(s + 4);
      v4u o = { pk2(a[0], a[1]), pk2(a[2], a[3]), pk2(b[0], b[1]), pk2(b[2], b[3]) };
      *(v4u*)d = o;
    }
  }
}

#define TIL 32      // edges per tile
#define LDX_S 136   // 128 + 8 pad shorts
#define LDH_S 264   // 256 + 8 pad shorts
#define LDP_S 20    // 16 slots + 4 pad floats
#define XBUF (TIL * LDX_S)   // 4352 shorts / buffer
#define HBUF (TIL * LDH_S)   // 8448 shorts / buffer
#define PBUF (TIL * LDP_S)   // 640 floats / buffer
#define SMEM_BYTES (2*XBUF*2 + 2*HBUF*2 + 2*PBUF*4)   // 56320 B -> 2 blocks/CU

// v19 = v18 with the register cap RESTORED to 256 (__launch_bounds__(512,2)).
// v18 autopsy: (512,4) capped VGPRs at 128 < the B-path's ~200 streaming
// demand -> allocator spilled weight state to scratch (VGPR=64, WRITE 56 MB,
// scratch re-reads blew L2 -> FETCH 1.68 GB, 480 us). v12/v15 prove these
// exact inner loops compile to 104-108 VGPR at cap 256 -- which is <= 128,
// so the HW scheduler still co-resides 2 blocks/CU at runtime:
//   LDS 2 x 56.3 = 112.6 <= 160 KB; 4 waves/SIMD x 108 = 432 <= 512 VGPRs.
// This finally gives a clean test of independent-barrier-group overlap
// (v16 showed same-group waves don't help; v17/v18 were compile artifacts):
// one block's barrier-drain windows filled by the other block's compute.
// Per-CU MFMA/LDS/gather totals identical to v12; FETCH must return to 94 MB.
__global__ __launch_bounds__(512, 2) void mlp_v19(
    const short* __restrict__ xub, const short* __restrict__ xmb,
    const void* __restrict__ eidx,
    const short* __restrict__ pW1, const short* __restrict__ pW2,
    const float* __restrict__ b1, const float* __restrict__ b2,
    const float* __restrict__ W3, const float* __restrict__ b3,
    float* __restrict__ out, int E)
{
  extern __shared__ __align__(16) char smem[];
  short* ldsX = (short*)smem;                       // [2][XBUF]
  short* ldsH = (short*)(smem + 2 * XBUF * 2);      // [2][HBUF]
  float* ldsP = (float*)(smem + 2 * XBUF * 2 + 2 * HBUF * 2); // [2][PBUF]

  const int t    = threadIdx.x;
  const int w    = t >> 6;
  const int lane = t & 63;
  const int quad = lane >> 4;
  const int lp   = lane & 15;
  const int wg   = w >> 1;
  const bool isA = (((w & 1) ^ ((w >> 2) & 1)) == 0);

  const unsigned* ew = (const unsigned*)eidx;
  unsigned oddw = (lane < 32) ? ew[2 * lane + 1] : 0u;
  const bool i64 = (__ballot(oddw != 0u) == 0ull);

  const int ntiles = (E + TIL - 1) / TIL;
  const int S   = (int)gridDim.x;
  const int bid = (int)blockIdx.x;
  const int Tb  = (ntiles - bid + S - 1) / S;
  const float bias3 = b3[0];

  if (isA) {
    // ===== producer: gather (bf16) + layer 1 (+ store on wg==0) =====
    const v8s* w1v = (const v8s*)pW1;
    v8s rW1[4][4];
#pragma unroll
    for (int mi = 0; mi < 4; ++mi)
#pragma unroll
      for (int kt = 0; kt < 4; ++kt)
        rW1[mi][kt] = w1v[(((wg * 4 + mi) * 4) + kt) * 64 + lane];
    v4f rb1[4];
#pragma unroll
    for (int mi = 0; mi < 4; ++mi)
      rb1[mi] = *(const v4f*)(b1 + wg * 64 + mi * 16 + quad * 4);

    const int ra = wg * 64 + lane;      // 0..255 : 8 threads/edge
    const int gi = ra >> 3;             // edge in tile 0..31
    const int gq = ra & 7;              // 8-feat chunk 0..7

    auto loadIdx = [&](int tl, int& row, int& col) {
      int gE = tl * TIL + gi;
      if (gE >= E || gE < 0) gE = 0;
      if (i64) {
        const long long* p = (const long long*)eidx;
        row = (int)p[gE]; col = (int)p[(long long)E + gE];
      } else {
        const int* p = (const int*)eidx;
        row = p[gE]; col = p[E + gE];
      }
    };

    v4u u0, m0;   // 8 bf16 per side
    auto issueUM = [&](int row, int col) {
      u0 = *(const v4u*)(xub + (size_t)row * 64 + gq * 8);
      m0 = *(const v4u*)(xmb + (size_t)col * 64 + gq * 8);
    };

    int rowN, colN;
    loadIdx(bid, rowN, colN);
    issueUM(rowN, colN);
    loadIdx(bid + S, rowN, colN);

    for (int k = 0; k <= Tb + 2; ++k) {
      __syncthreads();
      const int pb = k & 1;
      const int tg = bid + k * S;

      // ---- commit prefetched bf16 features -> ldsX[pb]
      if (k < Tb) {
        short* px = &ldsX[pb * XBUF + gi * LDX_S + gq * 8];
        *(v4u*)(px)      = u0;   // user  -> k 0..63
        *(v4u*)(px + 64) = m0;   // movie -> k 64..127
      }
      // ---- prefetch features(t_{k+1}), indices(t_{k+2})
      if (k + 1 < Tb) {
        issueUM(rowN, colN);
        loadIdx(tg + 2 * S, rowN, colN);
      }

      // ---- reduce + store tile t3 from ldsP[pb^1] (wave wg==0, lane<32)
      const int t3 = tg - 3 * S;
      if (t3 >= 0 && wg == 0 && lane < TIL) {
        const v4f* pp = (const v4f*)&ldsP[(pb ^ 1) * PBUF + lane * LDP_S];
        float r = bias3;
#pragma unroll
        for (int c = 0; c < 4; ++c) {
          v4f p = pp[c];
          r += (p[0] + p[1]) + (p[2] + p[3]);
        }
        int o = t3 * TIL + lane;
        if (o < E) out[o] = r;
      }

      // ---- layer 1 of t1 : ldsX[pb^1] -> ldsH[pb^1]
      const int t1 = tg - S;
      if (t1 >= 0 && t1 < ntiles) {
        const short* xb = &ldsX[(pb ^ 1) * XBUF];
        v4f acc[4][2];
#pragma unroll
        for (int mi = 0; mi < 4; ++mi) { acc[mi][0] = rb1[mi]; acc[mi][1] = rb1[mi]; }
        __builtin_amdgcn_s_setprio(1);
#pragma unroll
        for (int kt = 0; kt < 4; ++kt) {
          v8s bf0 = *(const v8s*)&xb[(lp) * LDX_S + kt * 32 + quad * 8];
          v8s bf1 = *(const v8s*)&xb[(16 + lp) * LDX_S + kt * 32 + quad * 8];
#pragma unroll
          for (int mi = 0; mi < 4; ++mi) {
            acc[mi][0] = __builtin_amdgcn_mfma_f32_16x16x32_bf16(rW1[mi][kt], bf0, acc[mi][0], 0, 0, 0);
            acc[mi][1] = __builtin_amdgcn_mfma_f32_16x16x32_bf16(rW1[mi][kt], bf1, acc[mi][1], 0, 0, 0);
          }
        }
        __builtin_amdgcn_s_setprio(0);
#pragma unroll
        for (int mi = 0; mi < 4; ++mi) {
          int nh0 = wg * 64 + mi * 16 + quad * 4;
#pragma unroll
          for (int nj = 0; nj < 2; ++nj) {
            int e = nj * 16 + lp;
            v4f v = acc[mi][nj];
            v2u pw; pw.x = pk2(fmaxf(v[0], 0.f), fmaxf(v[1], 0.f));
            pw.y = pk2(fmaxf(v[2], 0.f), fmaxf(v[3], 0.f));
            *(v2u*)&ldsH[(pb ^ 1) * HBUF + e * LDH_S + nh0] = pw;
          }
        }
      }
    }
  } else {
    // ===== consumer: layer 2 + bias/ReLU + W3 fold =====
    const v8s* w2v = (const v8s*)pW2;
    v8s rW2[4][8];
#pragma unroll
    for (int mi = 0; mi < 4; ++mi)
#pragma unroll
      for (int kt = 0; kt < 8; ++kt)
        rW2[mi][kt] = w2v[(((wg * 4 + mi) * 8) + kt) * 64 + lane];
    v4f rb2[4], rw3[4];
#pragma unroll
    for (int mi = 0; mi < 4; ++mi) {
      int nh0 = wg * 64 + mi * 16 + quad * 4;
      rb2[mi] = *(const v4f*)(b2 + nh0);
      rw3[mi] = *(const v4f*)(W3 + nh0);
    }

    for (int k = 0; k <= Tb + 2; ++k) {
      __syncthreads();
      const int pb = k & 1;
      const int tg = bid + k * S;
      const int t2 = tg - 2 * S;
      if (t2 >= 0 && t2 < ntiles) {
        const short* hbr = &ldsH[pb * HBUF];
        float* pPw = &ldsP[pb * PBUF];
        v4f acc2[4][2];
#pragma unroll
        for (int mi = 0; mi < 4; ++mi) { acc2[mi][0] = rb2[mi]; acc2[mi][1] = rb2[mi]; }
        __builtin_amdgcn_s_setprio(1);
#pragma unroll
        for (int kt = 0; kt < 8; ++kt) {
          v8s bf0 = *(const v8s*)&hbr[(lp) * LDH_S + kt * 32 + quad * 8];
          v8s bf1 = *(const v8s*)&hbr[(16 + lp) * LDH_S + kt * 32 + quad * 8];
#pragma unroll
          for (int mi = 0; mi < 4; ++mi) {
            acc2[mi][0] = __builtin_amdgcn_mfma_f32_16x16x32_bf16(rW2[mi][kt], bf0, acc2[mi][0], 0, 0, 0);
            acc2[mi][1] = __builtin_amdgcn_mfma_f32_16x16x32_bf16(rW2[mi][kt], bf1, acc2[mi][1], 0, 0, 0);
          }
        }
        __builtin_amdgcn_s_setprio(0);
        float s0 = 0.f, s1 = 0.f;
#pragma unroll
        for (int mi = 0; mi < 4; ++mi) {
#pragma unroll
          for (int r = 0; r < 4; ++r) {
            s0 += fmaxf(acc2[mi][0][r], 0.f) * rw3[mi][r];
            s1 += fmaxf(acc2[mi][1][r], 0.f) * rw3[mi][r];
          }
        }
        pPw[(lp) * LDP_S + wg * 4 + quad] = s0;
        pPw[(16 + lp) * LDP_S + wg * 4 + quad] = s1;
      }
    }
  }
}

extern "C" void kernel_launch(void* const* d_in, const int* in_sizes, int n_in,
                              void* d_out, int out_size, void* d_ws, size_t ws_size,
                              hipStream_t stream) {
  const float* xu  = (const float*)d_in[0];
  const float* xm  = (const float*)d_in[1];
  const void*  ei  = d_in[2];
  const float* W1  = (const float*)d_in[3];
  const float* b1  = (const float*)d_in[4];
  const float* W2  = (const float*)d_in[5];
  const float* b2  = (const float*)d_in[6];
  const float* W3  = (const float*)d_in[7];
  const float* b3  = (const float*)d_in[8];
  float* out = (float*)d_out;

  const int E  = in_sizes[2] / 2;
  const int Nu = in_sizes[0] / 64;
  const int Nm = in_sizes[1] / 64;

  short* pW1 = (short*)d_ws;          // 64 KB
  short* pW2 = pW1 + 32768;           // 128 KB
  short* xub = (short*)((char*)d_ws + 196608);
  short* xmb = xub + (size_t)Nu * 64;

  const int cvt_blocks = ((Nu + Nm) * 8 + 255) / 256;
  hipLaunchKernelGGL(prep, dim3(384 + cvt_blocks), dim3(256), 0, stream,
                     W1, W2, xu, xm, pW1, pW2, xub, xmb, Nu, Nm);

  hipFuncSetAttribute((const void*)mlp_v19,
                      hipFuncAttributeMaxDynamicSharedMemorySize, SMEM_BYTES);

  const int ntiles = (E + TIL - 1) / TIL;
  const int nblk = ntiles < 512 ? ntiles : 512;   // 2 blocks/CU
  hipLaunchKernelGGL(mlp_v19, dim3(nblk), dim3(512), SMEM_BYTES, stream,
                     xub, xmb, ei, pW1, pW2, b1, b2, W3, b3, out, E);
}